// Round 4
// baseline (75.414 us; speedup 1.0000x reference)
//
#include <hip/hip_runtime.h>

// WaveletFeatures: pywt.wavedec(x, 'db4', level=3, mode='symmetric') per row.
// out = concat([cA3, cD3, cD2, cD1]), each [B, Mk] row-major, flat fp32.
// y[m] = sum_{s=0..7} f[s] * x_sym[2m+1-s];  sym: o<0 -> -1-o ; o>=n -> 2n-1-o.
//
// R4: back to NT=256 / no reg clamp (R3 post-mortem: launch_bounds(512,8)
// choked VGPR to 28 and serialized loads; nt scalar stores amplified WRITE
// 131->203MB). Level 1 now W16 per thread: 10 dwordx4 issued back-to-back
// (160B/lane in flight, 2.5x R2) then two W8 compute halves so a/d register
// lifetimes stay short. Level 2 W8 (6 ds_read_b128 in flight). Normal stores
// (L2 merges the stride-scattered dword stores; rows are odd-length so
// vector stores can't align).

constexpr int N0 = 8192;
constexpr int M1 = 4099;  // floor((8192+7)/2)
constexpr int M2 = 2053;
constexpr int M3 = 1030;
constexpr int NT = 256;

__device__ __forceinline__ int symidx(int o, int n) {
    if (o < 0) o = -1 - o;
    if (o >= n) o = 2 * n - 1 - o;  // single reflection (overhang <= 6)
    return o;
}

// 4 output pairs from w[k] = in[2*i0 - 8 + k]: y[i0+j] = sum_t RF[t]*w[2j+2+t]
__device__ __forceinline__ void compute4(const float* __restrict__ w,
                                         float* __restrict__ a,
                                         float* __restrict__ d) {
    constexpr float RLO[8] = {0.23037781330885523f,  0.7148465705525415f,
                              0.6308807679295904f,   -0.02798376941698385f,
                              -0.18703481171888114f, 0.030841381835986965f,
                              0.032883011666982945f, -0.010597401784997278f};
    constexpr float RHI[8] = {-0.010597401784997278f, -0.032883011666982945f,
                              0.030841381835986965f,  0.18703481171888114f,
                              -0.02798376941698385f,  -0.6308807679295904f,
                              0.7148465705525415f,    -0.23037781330885523f};
#pragma unroll
    for (int j = 0; j < 4; ++j) {
        float aj = 0.f, dj = 0.f;
#pragma unroll
        for (int t = 0; t < 8; ++t) {
            const float v = w[2 * j + 2 + t];
            aj = fmaf(RLO[t], v, aj);
            dj = fmaf(RHI[t], v, dj);
        }
        a[j] = aj;
        d[j] = dj;
    }
}

__device__ __forceinline__ void edge_pair(const float* in, int n, int i,
                                          float& a, float& d) {
    constexpr float LO[8] = {
        -0.010597401784997278f, 0.032883011666982945f, 0.030841381835986965f,
        -0.18703481171888114f,  -0.02798376941698385f, 0.6308807679295904f,
        0.7148465705525415f,    0.23037781330885523f};
    constexpr float HI[8] = {
        -0.23037781330885523f,  0.7148465705525415f,   -0.6308807679295904f,
        -0.02798376941698385f,  0.18703481171888114f,  0.030841381835986965f,
        -0.032883011666982945f, -0.010597401784997278f};
    a = 0.f;
    d = 0.f;
#pragma unroll
    for (int s = 0; s < 8; ++s) {
        const float v = in[symidx(2 * i + 1 - s, n)];
        a = fmaf(LO[s], v, a);
        d = fmaf(HI[s], v, d);
    }
}

__global__ __launch_bounds__(NT) void WaveletFeatures_77214922047612_kernel(
    const float* __restrict__ x, float* __restrict__ out, int B) {
    __shared__ __align__(16) float s1[M1 + 1];  // cA1
    __shared__ __align__(16) float s2[M2 + 3];  // cA2

    const int row = blockIdx.x;
    const int tid = threadIdx.x;
    const float* xr = x + (size_t)row * N0;

    float* ca3 = out + (size_t)row * M3;
    float* cd3 = out + (size_t)B * M3 + (size_t)row * M3;
    float* cd2 = out + 2 * (size_t)B * M3 + (size_t)row * M2;
    float* cd1 = out + (size_t)B * (2 * M3 + M2) + (size_t)row * M1;

    // ---- level 1: x (global, n=8192) -> cA1 in s1, cD1 -> global ---------
    // W16 per thread: outputs i0..i0+15, i0 = 4+16*tid, tid<255 (4..4083).
    if (tid < 255) {
        const int i0 = 4 + 16 * tid;
        float w[40];  // x[2*i0-8 .. 2*i0+31]
        const float4* p = reinterpret_cast<const float4*>(xr + 2 * i0 - 8);
#pragma unroll
        for (int k = 0; k < 10; ++k)  // 10 loads issued back-to-back
            *reinterpret_cast<float4*>(&w[4 * k]) = p[k];
#pragma unroll
        for (int h = 0; h < 2; ++h) {  // two W8 halves: short a/d lifetimes
            float a[8], d[8];
            compute4(w + 16 * h, a, d);
            compute4(w + 16 * h + 8, a + 4, d + 4);
            const int o = i0 + 8 * h;
            *reinterpret_cast<float4*>(&s1[o]) =
                make_float4(a[0], a[1], a[2], a[3]);
            *reinterpret_cast<float4*>(&s1[o + 4]) =
                make_float4(a[4], a[5], a[6], a[7]);
#pragma unroll
            for (int j = 0; j < 8; ++j) cd1[o + j] = d[j];
        }
    }
    if (tid < 19) {  // edges: {0..3, 4084..4098}
        const int i = tid < 4 ? tid : 4080 + tid;
        float a, d;
        edge_pair(xr, N0, i, a, d);
        s1[i] = a;
        cd1[i] = d;
    }
    __syncthreads();

    // ---- level 2: s1 (n=4099) -> cA2 in s2, cD2 -> global ----------------
    // W8 per thread: i0 = 4+8*tid, tid<255 (covers 4..2043).
    if (tid < 255) {
        const int i0 = 4 + 8 * tid;
        float w[24];
        const float4* p = reinterpret_cast<const float4*>(&s1[2 * i0 - 8]);
#pragma unroll
        for (int k = 0; k < 6; ++k)
            *reinterpret_cast<float4*>(&w[4 * k]) = p[k];
        float a[8], d[8];
        compute4(w, a, d);
        compute4(w + 8, a + 4, d + 4);
        *reinterpret_cast<float4*>(&s2[i0]) = make_float4(a[0], a[1], a[2], a[3]);
        *reinterpret_cast<float4*>(&s2[i0 + 4]) =
            make_float4(a[4], a[5], a[6], a[7]);
#pragma unroll
        for (int j = 0; j < 8; ++j) cd2[i0 + j] = d[j];
    }
    if (tid < 13) {  // edges: {0..3, 2044..2052}
        const int i = tid < 4 ? tid : 2040 + tid;
        float a, d;
        edge_pair(s1, M1, i, a, d);
        s2[i] = a;
        cd2[i] = d;
    }
    __syncthreads();

    // ---- level 3: s2 (n=2053) -> cA3, cD3 -> global ----------------------
    if (tid < 255) {
        const int i0 = 4 + 4 * tid;
        float w[16];
        const float4* p = reinterpret_cast<const float4*>(&s2[2 * i0 - 8]);
#pragma unroll
        for (int k = 0; k < 4; ++k)
            *reinterpret_cast<float4*>(&w[4 * k]) = p[k];
        float a[4], d[4];
        compute4(w, a, d);
#pragma unroll
        for (int j = 0; j < 4; ++j) {
            ca3[i0 + j] = a[j];
            cd3[i0 + j] = d[j];
        }
    }
    if (tid < 10) {  // edges: {0..3, 1024..1029}
        const int i = tid < 4 ? tid : 1020 + tid;
        float a, d;
        edge_pair(s2, M2, i, a, d);
        ca3[i] = a;
        cd3[i] = d;
    }
}

extern "C" void kernel_launch(void* const* d_in, const int* in_sizes, int n_in,
                              void* d_out, int out_size, void* d_ws,
                              size_t ws_size, hipStream_t stream) {
    const float* x = (const float*)d_in[0];
    float* out = (float*)d_out;
    const int B = in_sizes[0] / N0;  // 4096
    WaveletFeatures_77214922047612_kernel<<<dim3(B), dim3(NT), 0, stream>>>(
        x, out, B);
}

// Round 6
// 47.185 us; speedup vs baseline: 1.5982x; 1.5982x over previous
//
#include <hip/hip_runtime.h>

// WaveletFeatures: pywt.wavedec(x, 'db4', level=3, mode='symmetric') per row.
// out = concat([cA3, cD3, cD2, cD1]), each [B, Mk] row-major, flat fp32.
// y[m] = sum_{s=0..7} f[s] * x_sym[2m+1-s];  sym: o<0 -> -1-o ; o>=n -> 2n-1-o.
//
// R6 = R5 with the nontemporal builtin fixed (needs a NATIVE clang vector
// type, not HIP_vector_type). Design rationale (R5): input (134MB) fits L3
// (256MB) but output writes (135MB) evict it -> steady-state FETCH 66MB.
// Aligned 16B nt stores mark output evict-first so input stays L3-resident
// across graph replays. R3 showed SCALAR nt stores amplify WRITE (no merge);
// all interior stores here are 16B-aligned dwordx4 nt. Odd row lengths force
// a per-row chunk phase: cD1 aligned at i=row(4), cD2 at i=-row(4), L3 at
// i=2row(4). Odd phases shift read base to 2 mod 4 -> one extra aligned
// float4 over-read with compile-time PAD (runtime pad would scratch-spill).

constexpr int N0 = 8192;
constexpr int M1 = 4099;  // floor((8192+7)/2)
constexpr int M2 = 2053;
constexpr int M3 = 1030;
constexpr int NT = 256;

typedef float vfloat4 __attribute__((ext_vector_type(4)));

__device__ __forceinline__ int symidx(int o, int n) {
    if (o < 0) o = -1 - o;
    if (o >= n) o = 2 * n - 1 - o;  // single reflection (overhang <= 6)
    return o;
}

// 4 output pairs from w[k] = in[2*i0 - 8 + k]: y[i0+j] = sum_t RF[t]*w[2j+2+t]
__device__ __forceinline__ void compute4(const float* __restrict__ w,
                                         float* __restrict__ a,
                                         float* __restrict__ d) {
    constexpr float RLO[8] = {0.23037781330885523f,  0.7148465705525415f,
                              0.6308807679295904f,   -0.02798376941698385f,
                              -0.18703481171888114f, 0.030841381835986965f,
                              0.032883011666982945f, -0.010597401784997278f};
    constexpr float RHI[8] = {-0.010597401784997278f, -0.032883011666982945f,
                              0.030841381835986965f,  0.18703481171888114f,
                              -0.02798376941698385f,  -0.6308807679295904f,
                              0.7148465705525415f,    -0.23037781330885523f};
#pragma unroll
    for (int j = 0; j < 4; ++j) {
        float aj = 0.f, dj = 0.f;
#pragma unroll
        for (int t = 0; t < 8; ++t) {
            const float v = w[2 * j + 2 + t];
            aj = fmaf(RLO[t], v, aj);
            dj = fmaf(RHI[t], v, dj);
        }
        a[j] = aj;
        d[j] = dj;
    }
}

// One interior chunk of 4 output pairs starting at i0 (phase via compile-time
// PAD in {0,2} so the window array stays in registers).
// Reads 4 (+1 if PAD) aligned float4 from in + 2*i0 - 8 - PAD.
template <int PAD>
__device__ __forceinline__ void chunk(const float* __restrict__ in, int i0,
                                      float* __restrict__ a,
                                      float* __restrict__ d) {
    float w[16 + (PAD ? 4 : 0)];
    const float4* p = reinterpret_cast<const float4*>(in + 2 * i0 - 8 - PAD);
    *reinterpret_cast<float4*>(&w[0]) = p[0];
    *reinterpret_cast<float4*>(&w[4]) = p[1];
    *reinterpret_cast<float4*>(&w[8]) = p[2];
    *reinterpret_cast<float4*>(&w[12]) = p[3];
    if constexpr (PAD != 0) *reinterpret_cast<float4*>(&w[16]) = p[4];
    compute4(w + PAD, a, d);
}

__device__ __forceinline__ void edge_pair(const float* in, int n, int i,
                                          float& a, float& d) {
    constexpr float LO[8] = {
        -0.010597401784997278f, 0.032883011666982945f, 0.030841381835986965f,
        -0.18703481171888114f,  -0.02798376941698385f, 0.6308807679295904f,
        0.7148465705525415f,    0.23037781330885523f};
    constexpr float HI[8] = {
        -0.23037781330885523f,  0.7148465705525415f,   -0.6308807679295904f,
        -0.02798376941698385f,  0.18703481171888114f,  0.030841381835986965f,
        -0.032883011666982945f, -0.010597401784997278f};
    a = 0.f;
    d = 0.f;
#pragma unroll
    for (int s = 0; s < 8; ++s) {
        const float v = in[symidx(2 * i + 1 - s, n)];
        a = fmaf(LO[s], v, a);
        d = fmaf(HI[s], v, d);
    }
}

__device__ __forceinline__ void ntst4(float* dst, float a0, float a1, float a2,
                                      float a3) {
    vfloat4 v = {a0, a1, a2, a3};
    __builtin_nontemporal_store(v, reinterpret_cast<vfloat4*>(dst));
}

__global__ __launch_bounds__(NT) void WaveletFeatures_77214922047612_kernel(
    const float* __restrict__ x, float* __restrict__ out, int B) {
    __shared__ __align__(16) float s1[M1 + 8];  // cA1 (+over-read pad)
    __shared__ __align__(16) float s2[M2 + 8];  // cA2

    const int row = blockIdx.x;
    const int tid = threadIdx.x;
    const int r4 = row & 3;
    const float* xr = x + (size_t)row * N0;

    float* ca3 = out + (size_t)row * M3;
    float* cd3 = out + (size_t)B * M3 + (size_t)row * M3;
    float* cd2 = out + 2 * (size_t)B * M3 + (size_t)row * M2;
    float* cd1 = out + (size_t)B * (2 * M3 + M2) + (size_t)row * M1;

    // ---- level 1: x (global, n=8192) -> cA1 in s1, cD1 -> global ---------
    {
        const int ph = r4;                       // cd1[i] 16B-aligned iff i=ph(4)
        const int lo = ph + 4;                   // first interior chunk start
        const int cap = (ph & 1) ? 4091 : 4092;  // load-safety: no OOB over-read
        const int C = (cap - lo) / 4 + 1;
        const int hi = lo + 4 * C;
        if (ph & 1) {
            for (int c = tid; c < C; c += NT) {
                const int i0 = lo + 4 * c;
                float a[4], d[4];
                chunk<2>(xr, i0, a, d);
                s1[i0] = a[0]; s1[i0 + 1] = a[1]; s1[i0 + 2] = a[2]; s1[i0 + 3] = a[3];
                ntst4(&cd1[i0], d[0], d[1], d[2], d[3]);
            }
        } else {
            for (int c = tid; c < C; c += NT) {
                const int i0 = lo + 4 * c;
                float a[4], d[4];
                chunk<0>(xr, i0, a, d);
                s1[i0] = a[0]; s1[i0 + 1] = a[1]; s1[i0 + 2] = a[2]; s1[i0 + 3] = a[3];
                ntst4(&cd1[i0], d[0], d[1], d[2], d[3]);
            }
        }
        const int nl = lo, nr = M1 - hi;
        if (tid < nl + nr) {
            const int i = tid < nl ? tid : hi + (tid - nl);
            float a, d;
            edge_pair(xr, N0, i, a, d);
            s1[i] = a;
            cd1[i] = d;
        }
    }
    __syncthreads();

    // ---- level 2: s1 (n=4099) -> cA2 in s2, cD2 -> global ----------------
    {
        const int ph = (4 - r4) & 3;  // cd2[i] aligned iff i = -row (4)
        const int lo = ph + 4;
        const int cap = 2045;  // over-read lands in s1 pad, always safe
        const int C = (cap - lo) / 4 + 1;
        const int hi = lo + 4 * C;
        if (ph & 1) {
            for (int c = tid; c < C; c += NT) {
                const int i0 = lo + 4 * c;
                float a[4], d[4];
                chunk<2>(s1, i0, a, d);
                s2[i0] = a[0]; s2[i0 + 1] = a[1]; s2[i0 + 2] = a[2]; s2[i0 + 3] = a[3];
                ntst4(&cd2[i0], d[0], d[1], d[2], d[3]);
            }
        } else {
            for (int c = tid; c < C; c += NT) {
                const int i0 = lo + 4 * c;
                float a[4], d[4];
                chunk<0>(s1, i0, a, d);
                s2[i0] = a[0]; s2[i0 + 1] = a[1]; s2[i0 + 2] = a[2]; s2[i0 + 3] = a[3];
                ntst4(&cd2[i0], d[0], d[1], d[2], d[3]);
            }
        }
        const int nl = lo, nr = M2 - hi;
        if (tid < nl + nr) {
            const int i = tid < nl ? tid : hi + (tid - nl);
            float a, d;
            edge_pair(s1, M1, i, a, d);
            s2[i] = a;
            cd2[i] = d;
        }
    }
    __syncthreads();

    // ---- level 3: s2 (n=2053) -> cA3, cD3 -> global ----------------------
    {
        const int ph = (2 * r4) & 3;  // in {0,2}: reads stay 16B-aligned (PAD=0)
        const int lo = ph + 4;
        const int cap = 1022;
        const int C = (cap - lo) / 4 + 1;
        const int hi = lo + 4 * C;
        for (int c = tid; c < C; c += NT) {
            const int i0 = lo + 4 * c;
            float a[4], d[4];
            chunk<0>(s2, i0, a, d);
            ntst4(&ca3[i0], a[0], a[1], a[2], a[3]);
            ntst4(&cd3[i0], d[0], d[1], d[2], d[3]);
        }
        const int nl = lo, nr = M3 - hi;
        if (tid < nl + nr) {
            const int i = tid < nl ? tid : hi + (tid - nl);
            float a, d;
            edge_pair(s2, M2, i, a, d);
            ca3[i] = a;
            cd3[i] = d;
        }
    }
}

extern "C" void kernel_launch(void* const* d_in, const int* in_sizes, int n_in,
                              void* d_out, int out_size, void* d_ws,
                              size_t ws_size, hipStream_t stream) {
    const float* x = (const float*)d_in[0];
    float* out = (float*)d_out;
    const int B = in_sizes[0] / N0;  // 4096
    WaveletFeatures_77214922047612_kernel<<<dim3(B), dim3(NT), 0, stream>>>(
        x, out, B);
}

// Round 7
// 47.116 us; speedup vs baseline: 1.6006x; 1.0015x over previous
//
#include <hip/hip_runtime.h>

// WaveletFeatures: pywt.wavedec(x, 'db4', level=3, mode='symmetric') per row.
// out = concat([cA3, cD3, cD2, cD1]), each [B, Mk] row-major, flat fp32.
// y[m] = sum_{s=0..7} f[s] * x_sym[2m+1-s];  sym: o<0 -> -1-o ; o>=n -> 2n-1-o.
//
// R7: segmented cascade. R6 post-mortem: nt stores didn't change FETCH (66MB
// steady); kernel is latency-bound (HBM 67%, VALU 15%, occ 53%) — too few
// resident blocks to cover barrier stalls. Fix: each block does HALF a row
// through all 3 levels (level-3 split [0,516)/[516,1030) propagated down with
// conv halos). LDS 25KB -> 12.4KB -> 8 blocks/CU = 32 waves = 100% occupancy,
// 8192 blocks. Seam values computed from in-span halo (extras, cA-only);
// true edges via symidx. LDS vector ops stay 16B-aligned via pad=lo&3 offset
// pointers (chunk grid i0 = 0 mod 4). Scalar global stores (R2 == R6 showed
// store vectorization is neutral).
//
// Per-seg ranges (derived + verified in session notes):
//  seg0: s1 span [0,2064)   cD1 own [0,2052)  chunks [4,2052)    extras [2052,2064)
//        s2 span [0,1032)   cD2 own [0,1028)  chunks [4,1028)    extras [1028,1032)
//        L3  own [0,516)    chunks [4,512)    edges [0,4)+[512,516)
//  seg1: s1 span [2046,4099) cD1 own [2052,4099) chunks [2052,4096) extras [2046,2052)
//        s2 span [1026,2053) cD2 own [1028,2053) chunks [1028,2048) extras [1026,1028)
//        L3  own [516,1030)  chunks [516,1024)  edges [1024,1030)

constexpr int N0 = 8192;
constexpr int M1 = 4099;  // floor((8192+7)/2)
constexpr int M2 = 2053;
constexpr int M3 = 1030;
constexpr int NT = 256;

__device__ __forceinline__ int symidx(int o, int n) {
    if (o < 0) o = -1 - o;
    if (o >= n) o = 2 * n - 1 - o;  // single reflection (overhang <= 6)
    return o;
}

// 4 output pairs from w[k] = in[2*i0 - 8 + k]: y[i0+j] = sum_t RF[t]*w[2j+2+t]
// (w[0], w[1] are unused by the math; they may hold garbage halo slots.)
__device__ __forceinline__ void compute4(const float* __restrict__ w,
                                         float* __restrict__ a,
                                         float* __restrict__ d) {
    constexpr float RLO[8] = {0.23037781330885523f,  0.7148465705525415f,
                              0.6308807679295904f,   -0.02798376941698385f,
                              -0.18703481171888114f, 0.030841381835986965f,
                              0.032883011666982945f, -0.010597401784997278f};
    constexpr float RHI[8] = {-0.010597401784997278f, -0.032883011666982945f,
                              0.030841381835986965f,  0.18703481171888114f,
                              -0.02798376941698385f,  -0.6308807679295904f,
                              0.7148465705525415f,    -0.23037781330885523f};
#pragma unroll
    for (int j = 0; j < 4; ++j) {
        float aj = 0.f, dj = 0.f;
#pragma unroll
        for (int t = 0; t < 8; ++t) {
            const float v = w[2 * j + 2 + t];
            aj = fmaf(RLO[t], v, aj);
            dj = fmaf(RHI[t], v, dj);
        }
        a[j] = aj;
        d[j] = dj;
    }
}

__device__ __forceinline__ void load16(const float* __restrict__ p,
                                       float* __restrict__ w) {
    *reinterpret_cast<float4*>(&w[0]) = *reinterpret_cast<const float4*>(p);
    *reinterpret_cast<float4*>(&w[4]) = *reinterpret_cast<const float4*>(p + 4);
    *reinterpret_cast<float4*>(&w[8]) = *reinterpret_cast<const float4*>(p + 8);
    *reinterpret_cast<float4*>(&w[12]) =
        *reinterpret_cast<const float4*>(p + 12);
}

__device__ __forceinline__ void edge_pair(const float* in, int n, int i,
                                          float& a, float& d) {
    constexpr float LO[8] = {
        -0.010597401784997278f, 0.032883011666982945f, 0.030841381835986965f,
        -0.18703481171888114f,  -0.02798376941698385f, 0.6308807679295904f,
        0.7148465705525415f,    0.23037781330885523f};
    constexpr float HI[8] = {
        -0.23037781330885523f,  0.7148465705525415f,   -0.6308807679295904f,
        -0.02798376941698385f,  0.18703481171888114f,  0.030841381835986965f,
        -0.032883011666982945f, -0.010597401784997278f};
    a = 0.f;
    d = 0.f;
#pragma unroll
    for (int s = 0; s < 8; ++s) {
        const float v = in[symidx(2 * i + 1 - s, n)];
        a = fmaf(LO[s], v, a);
        d = fmaf(HI[s], v, d);
    }
}

__global__ __launch_bounds__(NT) void WaveletFeatures_77214922047612_kernel(
    const float* __restrict__ x, float* __restrict__ out, int B) {
    __shared__ __align__(16) float s1buf[2068];  // cA1 segment (+pad)
    __shared__ __align__(16) float s2buf[1036];  // cA2 segment (+pad)

    const int bid = blockIdx.x;
    const int row = bid >> 1;
    const int seg = bid & 1;
    const int tid = threadIdx.x;
    const float* xr = x + (size_t)row * N0;

    float* ca3 = out + (size_t)row * M3;
    float* cd3 = out + (size_t)B * M3 + (size_t)row * M3;
    float* cd2 = out + 2 * (size_t)B * M3 + (size_t)row * M2;
    float* cd1 = out + (size_t)B * (2 * M3 + M2) + (size_t)row * M1;

    const int lo1 = seg ? 2046 : 0;
    const int lo2 = seg ? 1026 : 0;
    // global-index addressing into the LDS segments; pad keeps 16B alignment
    float* const s1g = s1buf + (lo1 & 3) - lo1;
    float* const s2g = s2buf + (lo2 & 3) - lo2;

    // ---- P1: x (global, n=8192) -> cA1 seg in s1g, owned cD1 -> global ----
    {
        const int allo = seg ? 2052 : 4;
        const int C = seg ? 511 : 512;
        for (int c = tid; c < C; c += NT) {
            const int i0 = allo + 4 * c;
            float w[16];
            load16(xr + 2 * i0 - 8, w);
            float a[4], d[4];
            compute4(w, a, d);
            *reinterpret_cast<float4*>(&s1g[i0]) =
                make_float4(a[0], a[1], a[2], a[3]);
            cd1[i0] = d[0]; cd1[i0 + 1] = d[1];
            cd1[i0 + 2] = d[2]; cd1[i0 + 3] = d[3];
        }
        const int nl = seg ? 0 : 4;   // left true-edge, both outputs
        const int nr = seg ? 3 : 0;   // right true-edge [4096,4099)
        const int ne = seg ? 6 : 12;  // halo extras, cA-only
        const int exlo = seg ? 2046 : 2052;
        if (tid < nl + nr + ne) {
            int i;
            bool both;
            if (tid < nl) { i = tid; both = true; }
            else if (tid < nl + nr) { i = 4096 + tid - nl; both = true; }
            else { i = exlo + tid - nl - nr; both = false; }
            float a, d;
            edge_pair(xr, N0, i, a, d);
            s1g[i] = a;
            if (both) cd1[i] = d;
        }
    }
    __syncthreads();

    // ---- P2: s1g (n=4099) -> cA2 seg in s2g, owned cD2 -> global ----------
    {
        const int allo = seg ? 1028 : 4;
        const int C = seg ? 255 : 256;
        for (int c = tid; c < C; c += NT) {
            const int i0 = allo + 4 * c;
            float w[16];
            load16(s1g + 2 * i0 - 8, w);
            float a[4], d[4];
            compute4(w, a, d);
            *reinterpret_cast<float4*>(&s2g[i0]) =
                make_float4(a[0], a[1], a[2], a[3]);
            cd2[i0] = d[0]; cd2[i0 + 1] = d[1];
            cd2[i0 + 2] = d[2]; cd2[i0 + 3] = d[3];
        }
        const int nl = seg ? 0 : 4;
        const int nr = seg ? 5 : 0;  // [2048,2053) true right edge
        const int ne = seg ? 2 : 4;
        const int exlo = seg ? 1026 : 1028;
        if (tid < nl + nr + ne) {
            int i;
            bool both;
            if (tid < nl) { i = tid; both = true; }
            else if (tid < nl + nr) { i = 2048 + tid - nl; both = true; }
            else { i = exlo + tid - nl - nr; both = false; }
            float a, d;
            edge_pair(s1g, M1, i, a, d);
            s2g[i] = a;
            if (both) cd2[i] = d;
        }
    }
    __syncthreads();

    // ---- P3: s2g (n=2053) -> owned cA3/cD3 -> global ----------------------
    {
        const int allo = seg ? 516 : 4;
        const int C = 127;
        for (int c = tid; c < C; c += NT) {
            const int i0 = allo + 4 * c;
            float w[16];
            load16(s2g + 2 * i0 - 8, w);
            float a[4], d[4];
            compute4(w, a, d);
#pragma unroll
            for (int j = 0; j < 4; ++j) {
                ca3[i0 + j] = a[j];
                cd3[i0 + j] = d[j];
            }
        }
        const int nl = seg ? 0 : 4;  // [0,4)
        const int nr = seg ? 6 : 4;  // seg0: [512,516); seg1: [1024,1030)
        const int alhi = seg ? 1024 : 512;
        if (tid < nl + nr) {
            const int i = tid < nl ? tid : alhi + tid - nl;
            float a, d;
            edge_pair(s2g, M2, i, a, d);
            ca3[i] = a;
            cd3[i] = d;
        }
    }
}

extern "C" void kernel_launch(void* const* d_in, const int* in_sizes, int n_in,
                              void* d_out, int out_size, void* d_ws,
                              size_t ws_size, hipStream_t stream) {
    const float* x = (const float*)d_in[0];
    float* out = (float*)d_out;
    const int B = in_sizes[0] / N0;  // 4096
    WaveletFeatures_77214922047612_kernel<<<dim3(2 * B), dim3(NT), 0, stream>>>(
        x, out, B);
}